// Round 3
// baseline (185.985 us; speedup 1.0000x reference)
//
#include <hip/hip_runtime.h>
#include <hip/hip_cooperative_groups.h>

namespace cg = cooperative_groups;

// Problem constants: VOCAB=50000, D=256, B=4, R=64, C=64, T=32.
#define VOCAB_SZ      50000
#define EMB_D         256
#define N_CELLS       16384            // B*R*C
#define TOK_T         32
#define N_TOKENS      (N_CELLS * TOK_T) // 524288
#define GRID_BLOCKS   1024             // 4 blocks/CU -> co-resident for grid.sync
#define BLOCK_THREADS 256

// Fused: phase 1 computes s[v] = E[v,:]·W (grid-stride, 4 rows/wave,
// 16 lanes/row); grid sync; phase 2 computes out[cell] = sum_t s[x_t] + b
// with 2 tokens/thread (int2, coalesced) and a 16-lane shuffle reduce.
__global__ void __launch_bounds__(BLOCK_THREADS, 4)
fused_kernel(const int* __restrict__ x, const float* __restrict__ E,
             const float* __restrict__ W, const float* __restrict__ b,
             float* __restrict__ out, float* __restrict__ s) {
    const int tid  = blockIdx.x * blockDim.x + threadIdx.x;   // 0..262143
    const int lane = threadIdx.x & 63;
    const int sub  = lane & 15;   // lane within 16-lane row group
    const int grp  = lane >> 4;   // which of 4 rows this wave handles
    const int wave = tid >> 6;
    const int nwaves = (GRID_BLOCKS * BLOCK_THREADS) >> 6;    // 4096

    // ---- Phase 1: s = E @ W ----
    const float4 w0 = *reinterpret_cast<const float4*>(W +   0 + sub * 4);
    const float4 w1 = *reinterpret_cast<const float4*>(W +  64 + sub * 4);
    const float4 w2 = *reinterpret_cast<const float4*>(W + 128 + sub * 4);
    const float4 w3 = *reinterpret_cast<const float4*>(W + 192 + sub * 4);

    const int ngroups = VOCAB_SZ / 4;   // 12500
    for (int g = wave; g < ngroups; g += nwaves) {
        const int row = g * 4 + grp;
        const float* er = E + (size_t)row * EMB_D;
        const float4 e0 = *reinterpret_cast<const float4*>(er +   0 + sub * 4);
        const float4 e1 = *reinterpret_cast<const float4*>(er +  64 + sub * 4);
        const float4 e2 = *reinterpret_cast<const float4*>(er + 128 + sub * 4);
        const float4 e3 = *reinterpret_cast<const float4*>(er + 192 + sub * 4);

        float p = e0.x*w0.x + e0.y*w0.y + e0.z*w0.z + e0.w*w0.w;
        p      += e1.x*w1.x + e1.y*w1.y + e1.z*w1.z + e1.w*w1.w;
        p      += e2.x*w2.x + e2.y*w2.y + e2.z*w2.z + e2.w*w2.w;
        p      += e3.x*w3.x + e3.y*w3.y + e3.z*w3.z + e3.w*w3.w;

        p += __shfl_xor(p, 1);
        p += __shfl_xor(p, 2);
        p += __shfl_xor(p, 4);
        p += __shfl_xor(p, 8);

        if (sub == 0) s[row] = p;
    }

    cg::this_grid().sync();

    // ---- Phase 2: out[cell] = sum_t s[x[cell,t]] + b ----
    // 262144 threads x 2 tokens = 524288 tokens, exact. 16 threads/cell.
    const int2 v = reinterpret_cast<const int2*>(x)[tid];
    float acc = s[v.x] + s[v.y];

    acc += __shfl_xor(acc, 1);
    acc += __shfl_xor(acc, 2);
    acc += __shfl_xor(acc, 4);
    acc += __shfl_xor(acc, 8);

    if (sub == 0) out[tid >> 4] = acc + b[0];
}

extern "C" void kernel_launch(void* const* d_in, const int* in_sizes, int n_in,
                              void* d_out, int out_size, void* d_ws, size_t ws_size,
                              hipStream_t stream) {
    const int*   x = (const int*)d_in[0];    // [B,R,C,T] int32
    const float* E = (const float*)d_in[1];  // [VOCAB, D] f32
    const float* W = (const float*)d_in[2];  // [D] f32
    const float* b = (const float*)d_in[3];  // [1] f32
    float* out = (float*)d_out;              // [B,R,C] f32
    float* s   = (float*)d_ws;               // [VOCAB] f32 scratch (200 KB)

    void* args[] = { (void*)&x, (void*)&E, (void*)&W, (void*)&b,
                     (void*)&out, (void*)&s };
    hipLaunchCooperativeKernel((const void*)fused_kernel,
                               dim3(GRID_BLOCKS), dim3(BLOCK_THREADS),
                               args, 0, stream);
}

// Round 4
// 92.166 us; speedup vs baseline: 2.0179x; 2.0179x over previous
//
#include <hip/hip_runtime.h>

// Problem constants: VOCAB=50000, D=256, B=4, R=64, C=64, T=32.
#define VOCAB_SZ 50000
#define EMB_D    256
#define N_CELLS  16384           // B*R*C
#define TOK_T    32

// Kernel 1: s[v] = dot(E[v,:], W).
// Exact grid: 3125 blocks x 4 waves = 12500 waves, one 4-row group per wave
// (50000 = 12500*4, no bounds check, no loop). 16 lanes per row, each lane
// loads 16 floats (4x float4 at col offsets 0/64/128/192), FMAs against W,
// 4-step shuffle reduce within the 16-lane group.
__global__ void __launch_bounds__(256)
vocab_dot_kernel(const float* __restrict__ E, const float* __restrict__ W,
                 float* __restrict__ s) {
    const int tid  = blockIdx.x * blockDim.x + threadIdx.x;
    const int wave = tid >> 6;           // 0..12499 = row group
    const int lane = threadIdx.x & 63;
    const int sub  = lane & 15;          // lane within 16-lane row group
    const int grp  = lane >> 4;          // which of the 4 rows in the group

    const float4 w0 = *reinterpret_cast<const float4*>(W +   0 + sub * 4);
    const float4 w1 = *reinterpret_cast<const float4*>(W +  64 + sub * 4);
    const float4 w2 = *reinterpret_cast<const float4*>(W + 128 + sub * 4);
    const float4 w3 = *reinterpret_cast<const float4*>(W + 192 + sub * 4);

    const int row = wave * 4 + grp;
    const float* er = E + (size_t)row * EMB_D;
    const float4 e0 = *reinterpret_cast<const float4*>(er +   0 + sub * 4);
    const float4 e1 = *reinterpret_cast<const float4*>(er +  64 + sub * 4);
    const float4 e2 = *reinterpret_cast<const float4*>(er + 128 + sub * 4);
    const float4 e3 = *reinterpret_cast<const float4*>(er + 192 + sub * 4);

    float p = e0.x*w0.x + e0.y*w0.y + e0.z*w0.z + e0.w*w0.w;
    p      += e1.x*w1.x + e1.y*w1.y + e1.z*w1.z + e1.w*w1.w;
    p      += e2.x*w2.x + e2.y*w2.y + e2.z*w2.z + e2.w*w2.w;
    p      += e3.x*w3.x + e3.y*w3.y + e3.z*w3.z + e3.w*w3.w;

    p += __shfl_xor(p, 1);
    p += __shfl_xor(p, 2);
    p += __shfl_xor(p, 4);
    p += __shfl_xor(p, 8);

    if (sub == 0) s[row] = p;
}

// Kernel 2: out[cell] = sum_t s[x[cell,t]] + b.
// 8 lanes per cell; each lane does ONE int4 load (4 tokens) -> fully
// coalesced x reads, 4 independent L2 gathers, 3-step shuffle reduce.
__global__ void __launch_bounds__(256)
cell_sum_kernel(const int* __restrict__ x, const float* __restrict__ s,
                const float* __restrict__ b, float* __restrict__ out) {
    const int tid = blockIdx.x * blockDim.x + threadIdx.x;  // 0..131071

    const int4 v = reinterpret_cast<const int4*>(x)[tid];
    float acc = s[v.x] + s[v.y] + s[v.z] + s[v.w];

    acc += __shfl_xor(acc, 1);
    acc += __shfl_xor(acc, 2);
    acc += __shfl_xor(acc, 4);

    if ((threadIdx.x & 7) == 0) out[tid >> 3] = acc + b[0];
}

extern "C" void kernel_launch(void* const* d_in, const int* in_sizes, int n_in,
                              void* d_out, int out_size, void* d_ws, size_t ws_size,
                              hipStream_t stream) {
    const int*   x = (const int*)d_in[0];    // [B,R,C,T] int32
    const float* E = (const float*)d_in[1];  // [VOCAB, D] f32
    const float* W = (const float*)d_in[2];  // [D] f32
    const float* b = (const float*)d_in[3];  // [1] f32
    float* out = (float*)d_out;              // [B,R,C] f32
    float* s   = (float*)d_ws;               // [VOCAB] f32 scratch (200 KB)

    // Kernel 1: exact cover, 50000 rows = 3125 blocks * 4 waves * 4 rows.
    vocab_dot_kernel<<<3125, 256, 0, stream>>>(E, W, s);

    // Kernel 2: 16384 cells * 8 lanes = 131072 threads -> 512 blocks.
    cell_sum_kernel<<<512, 256, 0, stream>>>(x, s, b, out);
}